// Round 1
// baseline (2976.305 us; speedup 1.0000x reference)
//
#include <hip/hip_runtime.h>
#include <cstdint>
#include <cstddef>

// MultiHeadAttention fp32 baseline (R1):
//   qkv = x @ W_qkv^T  -> split heads -> causal softmax(QK^T) V -> ctx @ W_out^T + b_out
// Shapes: x[2,2048,1024], W_qkv[3072,1024], W_out[1024,1024], b_out[1024], out[2,2048,1024]
// ws layout (floats): Q | K | V (each [2][16][2048][64]) | CTX ([2][2048][16][64]) = 64 MB total.

#define NH   16
#define HD   64
#define SEQ  2048
#define BATCH 2
#define DIN  1024

// ---------------------------------------------------------------------------
// Tiled NT GEMM: C[m,n] = sum_k A[m,k] * W[n,k]
// BM=BN=64, BK=32, 256 threads, 4x4 acc per thread.
// QKV=true : scatter C into Q/K/V head-major buffers (n-tile = one head slice)
// QKV=false: C + bias -> O0 row-major [M,1024]
// ---------------------------------------------------------------------------
template <bool QKV>
__global__ __launch_bounds__(256) void gemm_nt(const float* __restrict__ A,
                                               const float* __restrict__ W,
                                               const float* __restrict__ bias,
                                               float* __restrict__ O0,
                                               float* __restrict__ O1,
                                               float* __restrict__ O2)
{
    // stride 68 keeps float4 reads 16B-aligned (68*4=272 % 16 == 0) and breaks
    // power-of-2 bank striding.
    __shared__ float As[32][68];
    __shared__ float Bs[32][68];

    const int tid = threadIdx.x;
    const int tx = tid & 15;        // 0..15 -> n sub-tile
    const int ty = tid >> 4;        // 0..15 -> m sub-tile
    const int m0 = blockIdx.y * 64;
    const int n0 = blockIdx.x * 64;

    const int lr = tid >> 3;        // 0..31 (row within tile)
    const int lc = (tid & 7) << 2;  // 0,4,...,28 (k within tile)

    const float* Ap = A + (size_t)(m0 + lr) * DIN + lc;
    const float* Wp = W + (size_t)(n0 + lr) * DIN + lc;

    float acc[4][4] = {};

    for (int k0 = 0; k0 < DIN; k0 += 32) {
        float4 a0 = *(const float4*)(Ap + k0);
        float4 a1 = *(const float4*)(Ap + k0 + (size_t)32 * DIN);
        float4 b0 = *(const float4*)(Wp + k0);
        float4 b1 = *(const float4*)(Wp + k0 + (size_t)32 * DIN);

        __syncthreads();  // previous iteration's reads complete
        As[lc + 0][lr] = a0.x; As[lc + 1][lr] = a0.y; As[lc + 2][lr] = a0.z; As[lc + 3][lr] = a0.w;
        As[lc + 0][lr + 32] = a1.x; As[lc + 1][lr + 32] = a1.y; As[lc + 2][lr + 32] = a1.z; As[lc + 3][lr + 32] = a1.w;
        Bs[lc + 0][lr] = b0.x; Bs[lc + 1][lr] = b0.y; Bs[lc + 2][lr] = b0.z; Bs[lc + 3][lr] = b0.w;
        Bs[lc + 0][lr + 32] = b1.x; Bs[lc + 1][lr + 32] = b1.y; Bs[lc + 2][lr + 32] = b1.z; Bs[lc + 3][lr + 32] = b1.w;
        __syncthreads();

        #pragma unroll
        for (int kk = 0; kk < 32; ++kk) {
            float4 av = *(const float4*)&As[kk][ty << 2];
            float4 bv = *(const float4*)&Bs[kk][tx << 2];
            float ar[4] = {av.x, av.y, av.z, av.w};
            float br[4] = {bv.x, bv.y, bv.z, bv.w};
            #pragma unroll
            for (int i = 0; i < 4; ++i)
                #pragma unroll
                for (int j = 0; j < 4; ++j)
                    acc[i][j] = fmaf(ar[i], br[j], acc[i][j]);
        }
    }

    if (QKV) {
        // n0 multiple of 64; 3072 columns = {q,k,v} x 16 heads x 64 dims.
        const int part = n0 >> 10;           // 0=q 1=k 2=v
        const int h    = (n0 & 1023) >> 6;   // head
        float* dstbase = (part == 0) ? O0 : (part == 1) ? O1 : O2;
        #pragma unroll
        for (int i = 0; i < 4; ++i) {
            const int m  = m0 + (ty << 2) + i;
            const int bb = m >> 11;
            const int ss = m & 2047;
            float* drow = dstbase + (((size_t)(bb * NH + h) * SEQ + ss) << 6);
            *(float4*)(drow + (tx << 2)) =
                make_float4(acc[i][0], acc[i][1], acc[i][2], acc[i][3]);
        }
    } else {
        const int n = n0 + (tx << 2);
        const float4 bv = *(const float4*)(bias + n);
        #pragma unroll
        for (int i = 0; i < 4; ++i) {
            const int m = m0 + (ty << 2) + i;
            *(float4*)(O0 + (size_t)m * 1024 + n) =
                make_float4(acc[i][0] + bv.x, acc[i][1] + bv.y,
                            acc[i][2] + bv.z, acc[i][3] + bv.w);
        }
    }
}

// ---------------------------------------------------------------------------
// Causal attention, NO 1/sqrt(d) scaling. One thread per query row.
// Q/K/V head-major [b][h][s][d]; ctx out [b][s][h][d] (row-major [M,1024]).
// Online softmax; o rescaled only when the running max improves.
// ---------------------------------------------------------------------------
__global__ __launch_bounds__(256) void attn_kernel(const float* __restrict__ Q,
                                                   const float* __restrict__ K,
                                                   const float* __restrict__ V,
                                                   float* __restrict__ CTX)
{
    const int b = blockIdx.z;
    const int h = blockIdx.y;
    const int q = blockIdx.x * 256 + threadIdx.x;

    const size_t base = (size_t)(b * NH + h) * SEQ * HD;
    const float4* Qp = (const float4*)(Q + base + (size_t)q * HD);

    float qr[HD];
    #pragma unroll
    for (int i = 0; i < 16; ++i) {
        float4 t = Qp[i];
        qr[4 * i + 0] = t.x; qr[4 * i + 1] = t.y;
        qr[4 * i + 2] = t.z; qr[4 * i + 3] = t.w;
    }

    float o[HD];
    #pragma unroll
    for (int i = 0; i < HD; ++i) o[i] = 0.f;
    float mrun = -3.4e38f;
    float lrun = 0.f;

    const float4* Kb = (const float4*)(K + base);
    const float4* Vb = (const float4*)(V + base);
    const int L = q + 1;

    for (int j = 0; j < L; ++j) {
        const float4* kr = Kb + (size_t)j * 16;
        float s0 = 0.f, s1 = 0.f, s2 = 0.f, s3 = 0.f;
        #pragma unroll
        for (int i = 0; i < 4; ++i) {
            float4 k0 = kr[4 * i + 0];
            float4 k1 = kr[4 * i + 1];
            float4 k2 = kr[4 * i + 2];
            float4 k3 = kr[4 * i + 3];
            s0 = fmaf(qr[16 * i + 0],  k0.x, s0); s0 = fmaf(qr[16 * i + 1],  k0.y, s0);
            s0 = fmaf(qr[16 * i + 2],  k0.z, s0); s0 = fmaf(qr[16 * i + 3],  k0.w, s0);
            s1 = fmaf(qr[16 * i + 4],  k1.x, s1); s1 = fmaf(qr[16 * i + 5],  k1.y, s1);
            s1 = fmaf(qr[16 * i + 6],  k1.z, s1); s1 = fmaf(qr[16 * i + 7],  k1.w, s1);
            s2 = fmaf(qr[16 * i + 8],  k2.x, s2); s2 = fmaf(qr[16 * i + 9],  k2.y, s2);
            s2 = fmaf(qr[16 * i + 10], k2.z, s2); s2 = fmaf(qr[16 * i + 11], k2.w, s2);
            s3 = fmaf(qr[16 * i + 12], k3.x, s3); s3 = fmaf(qr[16 * i + 13], k3.y, s3);
            s3 = fmaf(qr[16 * i + 14], k3.z, s3); s3 = fmaf(qr[16 * i + 15], k3.w, s3);
        }
        const float sc = (s0 + s1) + (s2 + s3);

        float p;
        if (sc > mrun) {
            const float alpha = __expf(mrun - sc);  // exp(-huge)=0 on first hit
            lrun = lrun * alpha + 1.f;
            mrun = sc;
            p = 1.f;
            #pragma unroll
            for (int i = 0; i < HD; ++i) o[i] *= alpha;
        } else {
            p = __expf(sc - mrun);
            lrun += p;
        }

        const float4* vr = Vb + (size_t)j * 16;
        #pragma unroll
        for (int i = 0; i < 16; ++i) {
            float4 v4 = vr[i];
            o[4 * i + 0] = fmaf(p, v4.x, o[4 * i + 0]);
            o[4 * i + 1] = fmaf(p, v4.y, o[4 * i + 1]);
            o[4 * i + 2] = fmaf(p, v4.z, o[4 * i + 2]);
            o[4 * i + 3] = fmaf(p, v4.w, o[4 * i + 3]);
        }
    }

    const float inv = 1.f / lrun;
    float* op = CTX + ((size_t)(b * SEQ + q) * NH + h) * HD;
    #pragma unroll
    for (int i = 0; i < 16; ++i) {
        *(float4*)(op + 4 * i) = make_float4(o[4 * i + 0] * inv, o[4 * i + 1] * inv,
                                             o[4 * i + 2] * inv, o[4 * i + 3] * inv);
    }
}

// ---------------------------------------------------------------------------
extern "C" void kernel_launch(void* const* d_in, const int* in_sizes, int n_in,
                              void* d_out, int out_size, void* d_ws, size_t ws_size,
                              hipStream_t stream)
{
    const float* x    = (const float*)d_in[0];   // [2,2048,1024]
    const float* Wqkv = (const float*)d_in[1];   // [3072,1024]
    const float* Wout = (const float*)d_in[2];   // [1024,1024]
    const float* bout = (const float*)d_in[3];   // [1024]
    float* out = (float*)d_out;
    float* ws  = (float*)d_ws;

    const size_t chunk = (size_t)BATCH * NH * SEQ * HD;  // 4,194,304 floats
    float* Qb  = ws;
    float* Kb  = ws + chunk;
    float* Vb  = ws + 2 * chunk;
    float* CTX = ws + 3 * chunk;

    dim3 blk(256);

    // QKV projection: M=4096, N=3072, K=1024
    gemm_nt<true><<<dim3(48, 64), blk, 0, stream>>>(x, Wqkv, nullptr, Qb, Kb, Vb);

    // Attention: one thread per (b,h,q) row
    attn_kernel<<<dim3(SEQ / 256, NH, BATCH), blk, 0, stream>>>(Qb, Kb, Vb, CTX);

    // Output projection: M=4096, N=1024, K=1024, + bias
    gemm_nt<false><<<dim3(16, 64), blk, 0, stream>>>(CTX, Wout, bout, out, nullptr, nullptr);
}

// Round 2
// 1268.534 us; speedup vs baseline: 2.3463x; 2.3463x over previous
//
#include <hip/hip_runtime.h>
#include <cstdint>
#include <cstddef>

// MultiHeadAttention fp32 (R2): tiled flash attention replaces thread-per-row.
//   qkv = x @ W_qkv^T  -> split heads -> causal softmax(QK^T) V -> ctx @ W_out^T + b_out
// Shapes: x[2,2048,1024], W_qkv[3072,1024], W_out[1024,1024], b_out[1024], out[2,2048,1024]
// ws layout (floats): Q | K | V (each [2][16][2048][64]) | CTX ([2][2048][16][64]) = 64 MB.

#define NH   16
#define HD   64
#define SEQ  2048
#define BATCH 2
#define DIN  1024

// ---------------------------------------------------------------------------
// Tiled NT GEMM: C[m,n] = sum_k A[m,k] * W[n,k]
// BM=BN=64, BK=32, 256 threads, 4x4 acc per thread.
// ---------------------------------------------------------------------------
template <bool QKV>
__global__ __launch_bounds__(256) void gemm_nt(const float* __restrict__ A,
                                               const float* __restrict__ W,
                                               const float* __restrict__ bias,
                                               float* __restrict__ O0,
                                               float* __restrict__ O1,
                                               float* __restrict__ O2)
{
    __shared__ float As[32][68];
    __shared__ float Bs[32][68];

    const int tid = threadIdx.x;
    const int tx = tid & 15;
    const int ty = tid >> 4;
    const int m0 = blockIdx.y * 64;
    const int n0 = blockIdx.x * 64;

    const int lr = tid >> 3;
    const int lc = (tid & 7) << 2;

    const float* Ap = A + (size_t)(m0 + lr) * DIN + lc;
    const float* Wp = W + (size_t)(n0 + lr) * DIN + lc;

    float acc[4][4] = {};

    for (int k0 = 0; k0 < DIN; k0 += 32) {
        float4 a0 = *(const float4*)(Ap + k0);
        float4 a1 = *(const float4*)(Ap + k0 + (size_t)32 * DIN);
        float4 b0 = *(const float4*)(Wp + k0);
        float4 b1 = *(const float4*)(Wp + k0 + (size_t)32 * DIN);

        __syncthreads();
        As[lc + 0][lr] = a0.x; As[lc + 1][lr] = a0.y; As[lc + 2][lr] = a0.z; As[lc + 3][lr] = a0.w;
        As[lc + 0][lr + 32] = a1.x; As[lc + 1][lr + 32] = a1.y; As[lc + 2][lr + 32] = a1.z; As[lc + 3][lr + 32] = a1.w;
        Bs[lc + 0][lr] = b0.x; Bs[lc + 1][lr] = b0.y; Bs[lc + 2][lr] = b0.z; Bs[lc + 3][lr] = b0.w;
        Bs[lc + 0][lr + 32] = b1.x; Bs[lc + 1][lr + 32] = b1.y; Bs[lc + 2][lr + 32] = b1.z; Bs[lc + 3][lr + 32] = b1.w;
        __syncthreads();

        #pragma unroll
        for (int kk = 0; kk < 32; ++kk) {
            float4 av = *(const float4*)&As[kk][ty << 2];
            float4 bv = *(const float4*)&Bs[kk][tx << 2];
            float ar[4] = {av.x, av.y, av.z, av.w};
            float br[4] = {bv.x, bv.y, bv.z, bv.w};
            #pragma unroll
            for (int i = 0; i < 4; ++i)
                #pragma unroll
                for (int j = 0; j < 4; ++j)
                    acc[i][j] = fmaf(ar[i], br[j], acc[i][j]);
        }
    }

    if (QKV) {
        const int part = n0 >> 10;
        const int h    = (n0 & 1023) >> 6;
        float* dstbase = (part == 0) ? O0 : (part == 1) ? O1 : O2;
        #pragma unroll
        for (int i = 0; i < 4; ++i) {
            const int m  = m0 + (ty << 2) + i;
            const int bb = m >> 11;
            const int ss = m & 2047;
            float* drow = dstbase + (((size_t)(bb * NH + h) * SEQ + ss) << 6);
            *(float4*)(drow + (tx << 2)) =
                make_float4(acc[i][0], acc[i][1], acc[i][2], acc[i][3]);
        }
    } else {
        const int n = n0 + (tx << 2);
        const float4 bv = *(const float4*)(bias + n);
        #pragma unroll
        for (int i = 0; i < 4; ++i) {
            const int m = m0 + (ty << 2) + i;
            *(float4*)(O0 + (size_t)m * 1024 + n) =
                make_float4(acc[i][0] + bv.x, acc[i][1] + bv.y,
                            acc[i][2] + bv.z, acc[i][3] + bv.w);
        }
    }
}

// ---------------------------------------------------------------------------
// Tiled causal flash attention, fp32, NO 1/sqrt(d) scaling.
// Grid: (32 q-tiles, 16 heads, 2 batch), 256 threads (4 waves).
// Lane layout: lane = row*4 + quarter; thread owns q-row (wave*16+row) and
// head-dims [quarter*16, quarter*16+16). Score = partial dot + shfl_xor(1,2).
// K/V 64x64 tiles staged in LDS (32 KB); softmax state replicated over the
// 4 quarter-lanes of a row (identical arithmetic => identical values).
// q-tiles dispatched biggest-first to smooth causal load imbalance.
// ---------------------------------------------------------------------------
__global__ __launch_bounds__(256) void attn_kernel(const float* __restrict__ Q,
                                                   const float* __restrict__ K,
                                                   const float* __restrict__ V,
                                                   float* __restrict__ CTX)
{
    __shared__ float Ks[64][64];
    __shared__ float Vs[64][64];

    const int b = blockIdx.z;
    const int h = blockIdx.y;
    const int qt = gridDim.x - 1 - blockIdx.x;  // biggest q-tiles first
    const int q0 = qt * 64;

    const int tid = threadIdx.x;
    const int wave = tid >> 6;
    const int lane = tid & 63;
    const int row  = lane >> 2;       // 0..15
    const int quarter = lane & 3;     // 0..3
    const int qrow = wave * 16 + row; // 0..63 local q row
    const int qglob = q0 + qrow;
    const int d0 = quarter << 4;      // 0,16,32,48

    const size_t base = (size_t)(b * NH + h) * SEQ * HD;

    // q fragment: 16 floats
    float qf[16];
    {
        const float4* qp = (const float4*)(Q + base + (size_t)qglob * HD + d0);
        #pragma unroll
        for (int i = 0; i < 4; ++i) {
            float4 t = qp[i];
            qf[4 * i + 0] = t.x; qf[4 * i + 1] = t.y;
            qf[4 * i + 2] = t.z; qf[4 * i + 3] = t.w;
        }
    }

    float o[16];
    #pragma unroll
    for (int i = 0; i < 16; ++i) o[i] = 0.f;
    float mrun = -1e30f;
    float lrun = 0.f;

    const int ntiles = qt + 1;
    for (int t = 0; t < ntiles; ++t) {
        const int j0 = t * 64;

        __syncthreads();  // previous tile's LDS reads complete
        #pragma unroll
        for (int i = 0; i < 4; ++i) {
            const int f = tid + (i << 8);
            const int r = f >> 4;
            const int c = (f & 15) << 2;
            const size_t g = base + (size_t)(j0 + r) * HD + c;
            *(float4*)&Ks[r][c] = *(const float4*)(K + g);
            *(float4*)&Vs[r][c] = *(const float4*)(V + g);
        }
        __syncthreads();

        // rows j with (j0 + j) <= qglob; uniform 64 for non-diagonal tiles
        const int jmax = min(64, qglob - j0 + 1);
        for (int j = 0; j < jmax; ++j) {
            float4 k0 = *(const float4*)&Ks[j][d0];
            float4 k1 = *(const float4*)&Ks[j][d0 + 4];
            float4 k2 = *(const float4*)&Ks[j][d0 + 8];
            float4 k3 = *(const float4*)&Ks[j][d0 + 12];
            float sa = 0.f, sb = 0.f;
            sa = fmaf(qf[0],  k0.x, sa); sb = fmaf(qf[1],  k0.y, sb);
            sa = fmaf(qf[2],  k0.z, sa); sb = fmaf(qf[3],  k0.w, sb);
            sa = fmaf(qf[4],  k1.x, sa); sb = fmaf(qf[5],  k1.y, sb);
            sa = fmaf(qf[6],  k1.z, sa); sb = fmaf(qf[7],  k1.w, sb);
            sa = fmaf(qf[8],  k2.x, sa); sb = fmaf(qf[9],  k2.y, sb);
            sa = fmaf(qf[10], k2.z, sa); sb = fmaf(qf[11], k2.w, sb);
            sa = fmaf(qf[12], k3.x, sa); sb = fmaf(qf[13], k3.y, sb);
            sa = fmaf(qf[14], k3.z, sa); sb = fmaf(qf[15], k3.w, sb);
            float s = sa + sb;
            s += __shfl_xor(s, 1, 64);
            s += __shfl_xor(s, 2, 64);   // full dot, replicated over 4 lanes

            float p;
            if (s > mrun) {
                const float alpha = __expf(mrun - s);  // 0 on first hit
                lrun = lrun * alpha + 1.f;
                mrun = s;
                p = 1.f;
                #pragma unroll
                for (int i = 0; i < 16; ++i) o[i] *= alpha;
            } else {
                p = __expf(s - mrun);
                lrun += p;
            }

            float4 v0 = *(const float4*)&Vs[j][d0];
            float4 v1 = *(const float4*)&Vs[j][d0 + 4];
            float4 v2 = *(const float4*)&Vs[j][d0 + 8];
            float4 v3 = *(const float4*)&Vs[j][d0 + 12];
            o[0]  = fmaf(p, v0.x, o[0]);  o[1]  = fmaf(p, v0.y, o[1]);
            o[2]  = fmaf(p, v0.z, o[2]);  o[3]  = fmaf(p, v0.w, o[3]);
            o[4]  = fmaf(p, v1.x, o[4]);  o[5]  = fmaf(p, v1.y, o[5]);
            o[6]  = fmaf(p, v1.z, o[6]);  o[7]  = fmaf(p, v1.w, o[7]);
            o[8]  = fmaf(p, v2.x, o[8]);  o[9]  = fmaf(p, v2.y, o[9]);
            o[10] = fmaf(p, v2.z, o[10]); o[11] = fmaf(p, v2.w, o[11]);
            o[12] = fmaf(p, v3.x, o[12]); o[13] = fmaf(p, v3.y, o[13]);
            o[14] = fmaf(p, v3.z, o[14]); o[15] = fmaf(p, v3.w, o[15]);
        }
    }

    const float inv = 1.f / lrun;
    float* op = CTX + ((size_t)(b * SEQ + qglob) * NH + h) * HD + d0;
    #pragma unroll
    for (int i = 0; i < 4; ++i) {
        *(float4*)(op + 4 * i) = make_float4(o[4 * i + 0] * inv, o[4 * i + 1] * inv,
                                             o[4 * i + 2] * inv, o[4 * i + 3] * inv);
    }
}

// ---------------------------------------------------------------------------
extern "C" void kernel_launch(void* const* d_in, const int* in_sizes, int n_in,
                              void* d_out, int out_size, void* d_ws, size_t ws_size,
                              hipStream_t stream)
{
    const float* x    = (const float*)d_in[0];   // [2,2048,1024]
    const float* Wqkv = (const float*)d_in[1];   // [3072,1024]
    const float* Wout = (const float*)d_in[2];   // [1024,1024]
    const float* bout = (const float*)d_in[3];   // [1024]
    float* out = (float*)d_out;
    float* ws  = (float*)d_ws;

    const size_t chunk = (size_t)BATCH * NH * SEQ * HD;  // 4,194,304 floats
    float* Qb  = ws;
    float* Kb  = ws + chunk;
    float* Vb  = ws + 2 * chunk;
    float* CTX = ws + 3 * chunk;

    dim3 blk(256);

    // QKV projection: M=4096, N=3072, K=1024
    gemm_nt<true><<<dim3(48, 64), blk, 0, stream>>>(x, Wqkv, nullptr, Qb, Kb, Vb);

    // Attention: 64-row q-tiles, K/V tiles shared via LDS
    attn_kernel<<<dim3(SEQ / 64, NH, BATCH), blk, 0, stream>>>(Qb, Kb, Vb, CTX);

    // Output projection: M=4096, N=1024, K=1024, + bias
    gemm_nt<false><<<dim3(16, 64), blk, 0, stream>>>(CTX, Wout, bout, out, nullptr, nullptr);
}

// Round 3
// 254.280 us; speedup vs baseline: 11.7048x; 4.9887x over previous
//
#include <hip/hip_runtime.h>
#include <cstdint>
#include <cstddef>

// MultiHeadAttention R3: full bf16-MFMA pipeline.
//   cast(x,Wqkv,Wout -> bf16) -> MFMA QKV GEMM -> MFMA flash attention -> MFMA out-proj
// Layouts (ws, bytes):
//   xb  @0        [4096][1024] bf16
//   wqb @8388608  [3072][1024] bf16
//   wob @14680064 [1024][1024] bf16
//   Qb/Kb/Vb @16M/24M/32M  [2][16][2048][64] bf16 (head-major)
//   CTX @41943040 [4096][1024] bf16  (row = b*2048+s, col = h*64+d)
// MFMA facts used (doc-verified): 16x16x32_bf16 frags A[m=lane&15][k=quad*8+i],
// B[n=lane&15][k=quad*8+i], C/D[row=quad*4+reg][col=lane&15].

typedef __attribute__((ext_vector_type(8))) short bf16x8;
typedef __attribute__((ext_vector_type(4))) float f32x4;

#define MFMA16(a, b, c) __builtin_amdgcn_mfma_f32_16x16x32_bf16((a), (b), (c), 0, 0, 0)

#define GLDS16(g, s)                                                        \
  __builtin_amdgcn_global_load_lds(                                         \
      (const __attribute__((address_space(1))) void*)(g),                   \
      (__attribute__((address_space(3))) void*)(s), 16, 0, 0)

static __device__ __forceinline__ unsigned short f2bf(float f) {
  unsigned int u = __builtin_bit_cast(unsigned int, f);
  u += 0x7FFFu + ((u >> 16) & 1u);   // round-to-nearest-even
  return (unsigned short)(u >> 16);
}

// all-reduce max over the 16-lane group (lane&15) via DPP row rotations (VALU-only)
static __device__ __forceinline__ float rowmax16(float x) {
  int v;
  v = __builtin_amdgcn_update_dpp(0, __builtin_bit_cast(int, x), 0x121, 0xf, 0xf, false);
  x = fmaxf(x, __builtin_bit_cast(float, v));
  v = __builtin_amdgcn_update_dpp(0, __builtin_bit_cast(int, x), 0x122, 0xf, 0xf, false);
  x = fmaxf(x, __builtin_bit_cast(float, v));
  v = __builtin_amdgcn_update_dpp(0, __builtin_bit_cast(int, x), 0x124, 0xf, 0xf, false);
  x = fmaxf(x, __builtin_bit_cast(float, v));
  v = __builtin_amdgcn_update_dpp(0, __builtin_bit_cast(int, x), 0x128, 0xf, 0xf, false);
  x = fmaxf(x, __builtin_bit_cast(float, v));
  return x;
}

// ---------------------------------------------------------------------------
// fp32 -> bf16 cast for x (1048576 float4), W_qkv (786432), W_out (262144)
// ---------------------------------------------------------------------------
__global__ __launch_bounds__(256) void cast_bf16(const float* __restrict__ x,
                                                 const float* __restrict__ wq,
                                                 const float* __restrict__ wo,
                                                 unsigned short* __restrict__ xb,
                                                 unsigned short* __restrict__ wqb,
                                                 unsigned short* __restrict__ wob)
{
  const int id = blockIdx.x * 256 + threadIdx.x;   // 0 .. 2097151
  const float* src;
  unsigned short* dst;
  int off;
  if (id < 1048576)            { src = x;  dst = xb;  off = id; }
  else if (id < 1048576 + 786432) { src = wq; dst = wqb; off = id - 1048576; }
  else                         { src = wo; dst = wob; off = id - (1048576 + 786432); }
  float4 v = ((const float4*)src)[off];
  ushort4 o;
  o.x = f2bf(v.x); o.y = f2bf(v.y); o.z = f2bf(v.z); o.w = f2bf(v.w);
  ((ushort4*)dst)[off] = o;
}

// ---------------------------------------------------------------------------
// MFMA GEMM: C[m,n] = sum_k A[m,k] * B[n,k]  (both row-major [*,1024] bf16)
// 128x128 tile, BK=32, 256 thr = 4 waves (2x2 of 64x64), 16 MFMAs/wave/iter.
// BK=32 rows = 64B -> frag reads hit all 32 banks, no swizzle needed.
// MODE 1: scatter to bf16 Q/K/V head-major. MODE 0: fp32 out + bias.
// ---------------------------------------------------------------------------
template <int MODE>
__global__ __launch_bounds__(256) void gemm_bt(const unsigned short* __restrict__ A,
                                               const unsigned short* __restrict__ B,
                                               const float* __restrict__ bias,
                                               float* __restrict__ OutF,
                                               unsigned short* __restrict__ Qb,
                                               unsigned short* __restrict__ Kb,
                                               unsigned short* __restrict__ Vb)
{
  __shared__ unsigned short Asm[128 * 32];
  __shared__ unsigned short Bsm[128 * 32];

  const int tid  = threadIdx.x;
  const int wave = tid >> 6, lane = tid & 63, quad = lane >> 4, col = lane & 15;
  const int wm = wave >> 1, wn = wave & 1;
  const int m0 = blockIdx.y * 128, n0 = blockIdx.x * 128;
  const int sr = lane >> 2, sc = lane & 3;   // staging: 16 rows x 4 chunks / instr

  f32x4 acc[4][4];
  #pragma unroll
  for (int i = 0; i < 4; ++i)
    #pragma unroll
    for (int j = 0; j < 4; ++j)
      #pragma unroll
      for (int r = 0; r < 4; ++r) acc[i][j][r] = 0.f;

  for (int k0 = 0; k0 < 1024; k0 += 32) {
    __syncthreads();
    #pragma unroll
    for (int ii = 0; ii < 2; ++ii) {
      const int r = wave * 32 + ii * 16 + sr;
      GLDS16(A + (size_t)(m0 + r) * 1024 + k0 + sc * 8, &Asm[(wave * 32 + ii * 16) * 32]);
      GLDS16(B + (size_t)(n0 + r) * 1024 + k0 + sc * 8, &Bsm[(wave * 32 + ii * 16) * 32]);
    }
    __syncthreads();

    bf16x8 af[4], bfr[4];
    #pragma unroll
    for (int mt = 0; mt < 4; ++mt)
      af[mt] = *(const bf16x8*)&Asm[(wm * 64 + mt * 16 + col) * 32 + quad * 8];
    #pragma unroll
    for (int nt = 0; nt < 4; ++nt)
      bfr[nt] = *(const bf16x8*)&Bsm[(wn * 64 + nt * 16 + col) * 32 + quad * 8];
    #pragma unroll
    for (int mt = 0; mt < 4; ++mt)
      #pragma unroll
      for (int nt = 0; nt < 4; ++nt)
        acc[mt][nt] = MFMA16(af[mt], bfr[nt], acc[mt][nt]);
  }

  if (MODE == 1) {
    // n in [0,3072): part = n>>10 (q/k/v), head = (n>>6)&15, d = n&63
    #pragma unroll
    for (int mt = 0; mt < 4; ++mt) {
      const int mbase = m0 + wm * 64 + mt * 16 + quad * 4;
      #pragma unroll
      for (int nt = 0; nt < 4; ++nt) {
        const int n = n0 + wn * 64 + nt * 16 + col;
        const int part = n >> 10, hh = (n >> 6) & 15, d = n & 63;
        unsigned short* dst = (part == 0) ? Qb : (part == 1) ? Kb : Vb;
        #pragma unroll
        for (int r = 0; r < 4; ++r) {
          const int m = mbase + r;
          const int bb = m >> 11, ss = m & 2047;
          dst[((size_t)(bb * 16 + hh) * 2048 + ss) * 64 + d] = f2bf(acc[mt][nt][r]);
        }
      }
    }
  } else {
    #pragma unroll
    for (int mt = 0; mt < 4; ++mt) {
      const int mbase = m0 + wm * 64 + mt * 16 + quad * 4;
      #pragma unroll
      for (int nt = 0; nt < 4; ++nt) {
        const int n = n0 + wn * 64 + nt * 16 + col;
        const float bv = bias[n];
        #pragma unroll
        for (int r = 0; r < 4; ++r)
          OutF[(size_t)(mbase + r) * 1024 + n] = acc[mt][nt][r] + bv;
      }
    }
  }
}

// ---------------------------------------------------------------------------
// MFMA flash attention (causal, NO 1/sqrt(d) scale), bf16 in/out, fp32 softmax.
// Block = 64 q rows (4 waves x 16), loop over 64-j chunks, 32-j MFMA steps.
// K in LDS as two [64][32] arrays (64B rows, conflict-free, global_load_lds).
// V^T in LDS [64 d][72-stride j] bf16, packed-pair b32 writes (conflict-free).
// P round-trips through per-wave LDS [16][32] (same-wave DS ordering; no barrier).
// Row-sum via MFMA against all-ones B (broadcasts sum to every lane).
// ---------------------------------------------------------------------------
__global__ __launch_bounds__(256) void attn_mfma(const unsigned short* __restrict__ Qb,
                                                 const unsigned short* __restrict__ Kb,
                                                 const unsigned short* __restrict__ Vb,
                                                 unsigned short* __restrict__ CTX)
{
  __shared__ unsigned short Ksm[2][64 * 32];
  __shared__ unsigned short Vsm[64 * 72];
  __shared__ unsigned short Psm[4][16 * 32];

  const int tid  = threadIdx.x;
  const int wave = tid >> 6, lane = tid & 63, quad = lane >> 4, col = lane & 15;
  const int b = blockIdx.z, h = blockIdx.y;
  const int qt = (int)gridDim.x - 1 - (int)blockIdx.x;   // biggest q-tiles first
  const int q0 = qt * 64;
  const size_t base = (size_t)(b * 16 + h) * (2048 * 64);

  // Q fragments (A-operand), rows q0 + wave*16 + (lane&15), k = d
  bf16x8 qf[2];
  {
    const int qrow = q0 + wave * 16 + col;
    qf[0] = *(const bf16x8*)(Qb + base + (size_t)qrow * 64 + quad * 8);
    qf[1] = *(const bf16x8*)(Qb + base + (size_t)qrow * 64 + 32 + quad * 8);
  }

  f32x4 oacc[4];
  #pragma unroll
  for (int dt = 0; dt < 4; ++dt)
    #pragma unroll
    for (int r = 0; r < 4; ++r) oacc[dt][r] = 0.f;
  float mr[4] = {-3e38f, -3e38f, -3e38f, -3e38f};
  float lr[4] = {0.f, 0.f, 0.f, 0.f};

  bf16x8 ones;
  #pragma unroll
  for (int i = 0; i < 8; ++i) ones[i] = (short)0x3F80;   // bf16 1.0

  const int vj2 = (tid & 31) * 2, vcg = tid >> 5;   // V-transpose assignment

  for (int ch = 0; ch <= qt; ++ch) {
    const int j0c = ch * 64;
    __syncthreads();
    // stage K chunk: wave stages its 16 rows of both d-halves
    #pragma unroll
    for (int dk = 0; dk < 2; ++dk) {
      GLDS16(Kb + base + (size_t)(j0c + wave * 16 + (lane >> 2)) * 64 + dk * 32 + (lane & 3) * 8,
             &Ksm[dk][wave * 16 * 32]);
    }
    // stage V^T: thread packs j-pair (vj2, vj2+1) for 8 d values
    {
      const unsigned short* g = Vb + base + (size_t)(j0c + vj2) * 64 + vcg * 8;
      bf16x8 va  = *(const bf16x8*)g;
      bf16x8 vb2 = *(const bf16x8*)(g + 64);
      #pragma unroll
      for (int i = 0; i < 8; ++i) {
        unsigned int w = (unsigned int)(unsigned short)va[i] |
                         ((unsigned int)(unsigned short)vb2[i] << 16);
        *(unsigned int*)&Vsm[(vcg * 8 + i) * 72 + vj2] = w;
      }
    }
    __syncthreads();

    #pragma unroll
    for (int half = 0; half < 2; ++half) {
      const int jloc = half * 32, jg0 = j0c + jloc;

      // S = Q K^T for 32 j's: two 16-j C-frags, accumulate over d halves
      f32x4 s0, s1;
      #pragma unroll
      for (int r = 0; r < 4; ++r) { s0[r] = 0.f; s1[r] = 0.f; }
      #pragma unroll
      for (int dk = 0; dk < 2; ++dk) {
        bf16x8 kf0 = *(const bf16x8*)&Ksm[dk][(jloc + col) * 32 + quad * 8];
        bf16x8 kf1 = *(const bf16x8*)&Ksm[dk][(jloc + 16 + col) * 32 + quad * 8];
        s0 = MFMA16(qf[dk], kf0, s0);
        s1 = MFMA16(qf[dk], kf1, s1);
      }

      // causal mask + tile row-max
      const int qgb = q0 + wave * 16 + quad * 4;
      float sm0[4], sm1[4], tmx[4];
      #pragma unroll
      for (int r = 0; r < 4; ++r) {
        const int qg = qgb + r;
        sm0[r] = (jg0 + col      <= qg) ? s0[r] : -1e30f;
        sm1[r] = (jg0 + 16 + col <= qg) ? s1[r] : -1e30f;
        tmx[r] = rowmax16(fmaxf(sm0[r], sm1[r]));
      }
      float al[4];
      #pragma unroll
      for (int r = 0; r < 4; ++r) {
        const float mn = fmaxf(mr[r], tmx[r]);
        al[r] = __expf(mr[r] - mn);
        mr[r] = mn;
      }
      // P = exp(S - m) -> per-wave LDS (C-layout write, A-layout read)
      #pragma unroll
      for (int r = 0; r < 4; ++r) {
        const int prow = (quad * 4 + r) * 32;
        Psm[wave][prow + col]      = f2bf(__expf(sm0[r] - mr[r]));
        Psm[wave][prow + 16 + col] = f2bf(__expf(sm1[r] - mr[r]));
      }
      // rescale running state
      #pragma unroll
      for (int dt = 0; dt < 4; ++dt)
        #pragma unroll
        for (int r = 0; r < 4; ++r) oacc[dt][r] *= al[r];
      #pragma unroll
      for (int r = 0; r < 4; ++r) lr[r] *= al[r];

      // read P as A-operand (same-wave DS ordering guarantees visibility)
      bf16x8 pf = *(const bf16x8*)&Psm[wave][col * 32 + quad * 8];

      // row-sum via ones-MFMA: every column of D = sum_j P[q][j]
      f32x4 zz;
      #pragma unroll
      for (int r = 0; r < 4; ++r) zz[r] = 0.f;
      f32x4 ls = MFMA16(pf, ones, zz);
      #pragma unroll
      for (int r = 0; r < 4; ++r) lr[r] += ls[r];

      // O += P V  (B-frag from V^T: n = d, k = j contiguous)
      #pragma unroll
      for (int dt = 0; dt < 4; ++dt) {
        bf16x8 vf = *(const bf16x8*)&Vsm[(dt * 16 + col) * 72 + jloc + quad * 8];
        oacc[dt] = MFMA16(pf, vf, oacc[dt]);
      }
    }
  }

  float inv[4];
  #pragma unroll
  for (int r = 0; r < 4; ++r) inv[r] = 1.f / lr[r];
  const int srow = q0 + wave * 16 + quad * 4;
  #pragma unroll
  for (int dt = 0; dt < 4; ++dt)
    #pragma unroll
    for (int r = 0; r < 4; ++r)
      CTX[(size_t)(b * 2048 + srow + r) * 1024 + h * 64 + dt * 16 + col] =
          f2bf(oacc[dt][r] * inv[r]);
}

// ---------------------------------------------------------------------------
extern "C" void kernel_launch(void* const* d_in, const int* in_sizes, int n_in,
                              void* d_out, int out_size, void* d_ws, size_t ws_size,
                              hipStream_t stream)
{
  const float* x    = (const float*)d_in[0];   // [2,2048,1024]
  const float* Wqkv = (const float*)d_in[1];   // [3072,1024]
  const float* Wout = (const float*)d_in[2];   // [1024,1024]
  const float* bout = (const float*)d_in[3];   // [1024]
  float* out = (float*)d_out;

  char* ws = (char*)d_ws;
  unsigned short* xb  = (unsigned short*)(ws);
  unsigned short* wqb = (unsigned short*)(ws + 8388608);
  unsigned short* wob = (unsigned short*)(ws + 14680064);
  unsigned short* Qb  = (unsigned short*)(ws + 16777216);
  unsigned short* Kb  = (unsigned short*)(ws + 25165824);
  unsigned short* Vb  = (unsigned short*)(ws + 33554432);
  unsigned short* CTX = (unsigned short*)(ws + 41943040);

  dim3 blk(256);

  cast_bf16<<<dim3(8192), blk, 0, stream>>>(x, Wqkv, Wout, xb, wqb, wob);

  // QKV projection: M=4096, N=3072, K=1024
  gemm_bt<1><<<dim3(24, 32), blk, 0, stream>>>(xb, wqb, nullptr, nullptr, Qb, Kb, Vb);

  // Flash attention: 64-row q-tiles
  attn_mfma<<<dim3(32, 16, 2), blk, 0, stream>>>(Qb, Kb, Vb, CTX);

  // Output projection: M=4096, N=1024, K=1024, + bias
  gemm_bt<0><<<dim3(8, 32), blk, 0, stream>>>(CTX, wob, bout, out, nullptr, nullptr, nullptr);
}